// Round 4
// baseline (150.741 us; speedup 1.0000x reference)
//
#include <hip/hip_runtime.h>
#include <math.h>

#define HH 512
#define WW 512
#define PHH 16
#define PWW 16
#define QQ 3
#define NHH 32
#define NWW 32
#define PP 1024
#define BB 64

// Transpose buffer geometry (floats): row stride 18 (16 data + 2 pad, keeps
// b64 writes 8B-aligned and banks spread), group stride 296 (= 16*18 + 8 pad
// so the 4 groups of a wave land at bank offsets 0/8/16/24 -> scalar column
// reads are 2 lanes/bank = free).
#define TROW 18
#define TGRP 296

// Compiler-only fence: prevents IR + machine-scheduler reordering of LDS ops.
// Correctness relies on the HW guarantee that LDS ops from one wave complete
// in issue order (cross-lane write->read within a wave needs no s_barrier).
__device__ __forceinline__ void wfence() {
  asm volatile("" ::: "memory");
  __builtin_amdgcn_sched_barrier(0);
}

// Butterfly with COMPILE-TIME twiddle index T (0..7), radix-2 DIT, n=16.
// SGN=+1: forward exp(-i 2pi jk/16); SGN=-1: unscaled inverse.
// Trivial twiddles (T=0: w=1; T=4: w=-+i; T=2/6: w=(+-c,+-c)) are specialized
// so the compiler emits adds/subs instead of full complex multiplies.
template <int SGN, int T>
__device__ __forceinline__ void bfly(float& ar, float& ai, float& br, float& bi) {
  float tr, ti;
  if constexpr (T == 0) {
    tr = br;
    ti = bi;
  } else if constexpr (T == 4) {
    if constexpr (SGN > 0) { tr = bi;  ti = -br; }
    else                   { tr = -bi; ti = br;  }
  } else if constexpr (T == 2) {
    constexpr float c = 0.70710678118654752440f;
    if constexpr (SGN > 0) { tr = c * (br + bi); ti = c * (bi - br); }
    else                   { tr = c * (br - bi); ti = c * (bi + br); }
  } else if constexpr (T == 6) {
    constexpr float c = 0.70710678118654752440f;
    if constexpr (SGN > 0) { tr = c * (bi - br);  ti = -c * (br + bi); }
    else                   { tr = -c * (br + bi); ti = c * (br - bi);  }
  } else {
    // T in {1,3,5,7}: full complex multiply with literal constants.
    constexpr float c1 = 0.92387953251128675613f;   // cos(pi/8)
    constexpr float s1 = 0.38268343236508977173f;   // sin(pi/8)
    constexpr float wr = (T == 1) ? c1 : (T == 3) ? s1 : (T == 5) ? -s1 : -c1;
    constexpr float wi0 = (T == 1) ? -s1 : (T == 3) ? -c1 : (T == 5) ? -c1 : -s1;
    constexpr float wi = (SGN > 0) ? wi0 : -wi0;
    tr = br * wr - bi * wi;
    ti = br * wi + bi * wr;
  }
  br = ar - tr;
  bi = ai - ti;
  ar = ar + tr;
  ai = ai + ti;
}

// Fully-unrolled in-register 16-point complex FFT with literal twiddles.
template <int SGN>
__device__ __forceinline__ void fft16(float re[16], float im[16]) {
#define SW_(a, b)                              \
  { float t = re[a]; re[a] = re[b]; re[b] = t; \
    t = im[a]; im[a] = im[b]; im[b] = t; }
  SW_(1, 8) SW_(2, 4) SW_(3, 12) SW_(5, 10) SW_(7, 14) SW_(11, 13)
#undef SW_
#define BF_(a, b, T) bfly<SGN, T>(re[a], im[a], re[b], im[b]);
  // len=2
  BF_(0, 1, 0) BF_(2, 3, 0) BF_(4, 5, 0) BF_(6, 7, 0)
  BF_(8, 9, 0) BF_(10, 11, 0) BF_(12, 13, 0) BF_(14, 15, 0)
  // len=4
  BF_(0, 2, 0) BF_(1, 3, 4) BF_(4, 6, 0) BF_(5, 7, 4)
  BF_(8, 10, 0) BF_(9, 11, 4) BF_(12, 14, 0) BF_(13, 15, 4)
  // len=8
  BF_(0, 4, 0) BF_(1, 5, 2) BF_(2, 6, 4) BF_(3, 7, 6)
  BF_(8, 12, 0) BF_(9, 13, 2) BF_(10, 14, 4) BF_(11, 15, 6)
  // len=16
  BF_(0, 8, 0) BF_(1, 9, 1) BF_(2, 10, 2) BF_(3, 11, 3)
  BF_(4, 12, 4) BF_(5, 13, 5) BF_(6, 14, 6) BF_(7, 15, 7)
#undef BF_
}

// Block: 256 threads = 16 groups x 16 threads. Block handles one patch p and
// 16 batch indices; group g -> batch b0+g, thread r -> row r of 16x16 patch.
// Each group is a quarter-wave, so the LDS transposes are wave-internal:
// no __syncthreads needed after Phase A.
// __launch_bounds__(256) ONLY: any waves-per-EU hint makes the allocator
// squeeze VGPRs below the live set and spill to scratch (round-2: VGPR=32,
// +123MB writes; round-3: VGPR=36, +20MB writes). Bare bound -> VGPR=52,
// zero spill (round-0 evidence).
__global__ __launch_bounds__(256) void psm_kernel(
    const float* __restrict__ x, const float* __restrict__ logits,
    const float* __restrict__ mu, const float* __restrict__ sigma,
    const float* __restrict__ bias, float* __restrict__ out) {
  __shared__ float S_lds[256];
  __shared__ float tbuf[16 * TGRP];  // 16 groups

  const int tid = threadIdx.x;
  const int p = blockIdx.x >> 2;
  const int b0 = (blockIdx.x & 3) << 4;
  const int g = tid >> 4;
  const int r = tid & 15;
  const int b = b0 + g;
  const int nh = p >> 5;
  const int nw = p & 31;

  // ---- Phase A: spectral filter S for this patch into LDS ----
  {
    const int fy_i = tid >> 4;
    const int fx_i = tid & 15;
    const float fy = (float)(fy_i < 8 ? fy_i : fy_i - 16) * (1.0f / 16.0f);
    const float fx = (float)(fx_i < 8 ? fx_i : fx_i - 16) * (1.0f / 16.0f);
    const float l0 = logits[p * QQ + 0];
    const float l1 = logits[p * QQ + 1];
    const float l2 = logits[p * QQ + 2];
    const float lm = fmaxf(l0, fmaxf(l1, l2));
    const float e0 = __expf(l0 - lm);
    const float e1 = __expf(l1 - lm);
    const float e2 = __expf(l2 - lm);
    const float inv = 1.0f / (e0 + e1 + e2);
    const float wq[3] = {e0 * inv, e1 * inv, e2 * inv};
    float s = 0.0f;
#pragma unroll
    for (int q = 0; q < QQ; ++q) {
      const float muy = mu[(p * QQ + q) * 2 + 0];
      const float mux = mu[(p * QQ + q) * 2 + 1];
      const float isy = 1.0f / sigma[(p * QQ + q) * 2 + 0];
      const float isx = 1.0f / sigma[(p * QQ + q) * 2 + 1];
      const float dy1 = (fy - muy) * isy;
      const float dx1 = (fx - mux) * isx;
      const float dy2 = (fy + muy) * isy;
      const float dx2 = (fx + mux) * isx;
      const float g1 = __expf(-0.5f * (dy1 * dy1 + dx1 * dx1));
      const float g2 = __expf(-0.5f * (dy2 * dy2 + dx2 * dx2));
      s += wq[q] * (g1 + g2);
    }
    // fold jitter and the ifft2 1/256 normalization into S
    S_lds[tid] = (s + 1e-6f) * (1.0f / 256.0f);
  }
  __syncthreads();  // the ONLY block barrier: S_lds is read by all waves

  // ---- Phase B: load row r of this (p,b) patch; forward row FFT ----
  const size_t rowoff =
      (size_t)b * (HH * WW) + (size_t)(nh * PHH + r) * WW + (size_t)(nw * PWW);
  const float* xrow = x + rowoff;
  float re[16], im[16];
#pragma unroll
  for (int c4 = 0; c4 < 4; ++c4) {
    const float4 v = ((const float4*)xrow)[c4];
    re[c4 * 4 + 0] = v.x;
    re[c4 * 4 + 1] = v.y;
    re[c4 * 4 + 2] = v.z;
    re[c4 * 4 + 3] = v.w;
  }
#pragma unroll
  for (int c = 0; c < 16; ++c) im[c] = 0.0f;  // literal zeros fold thru stage 1-2

  fft16<1>(re, im);

  // ---- Phase C: transpose via wave-local LDS (b64 row writes, b32 col reads)
  float* m = &tbuf[g * TGRP];
#pragma unroll
  for (int c2 = 0; c2 < 8; ++c2) {
    float2 v;
    v.x = re[2 * c2 + 0];
    v.y = re[2 * c2 + 1];
    *(float2*)&m[r * TROW + 2 * c2] = v;
  }
  wfence();
#pragma unroll
  for (int k = 0; k < 16; ++k) re[k] = m[k * TROW + r];
  wfence();
#pragma unroll
  for (int c2 = 0; c2 < 8; ++c2) {
    float2 v;
    v.x = im[2 * c2 + 0];
    v.y = im[2 * c2 + 1];
    *(float2*)&m[r * TROW + 2 * c2] = v;
  }
  wfence();
#pragma unroll
  for (int k = 0; k < 16; ++k) im[k] = m[k * TROW + r];
  wfence();

  // ---- Phase D: column FFT, multiply by S, inverse column FFT ----
  fft16<1>(re, im);
#pragma unroll
  for (int k = 0; k < 16; ++k) {
    const float s = S_lds[k * 16 + r];
    re[k] *= s;
    im[k] *= s;
  }
  fft16<-1>(re, im);

  // ---- Phase E: transpose back. Write columns (scalar), read rows (b64) ----
#pragma unroll
  for (int k = 0; k < 16; ++k) m[k * TROW + r] = re[k];
  wfence();
#pragma unroll
  for (int c2 = 0; c2 < 8; ++c2) {
    const float2 v = *(const float2*)&m[r * TROW + 2 * c2];
    re[2 * c2 + 0] = v.x;
    re[2 * c2 + 1] = v.y;
  }
  wfence();
#pragma unroll
  for (int k = 0; k < 16; ++k) m[k * TROW + r] = im[k];
  wfence();
#pragma unroll
  for (int c2 = 0; c2 < 8; ++c2) {
    const float2 v = *(const float2*)&m[r * TROW + 2 * c2];
    im[2 * c2 + 0] = v.x;
    im[2 * c2 + 1] = v.y;
  }

  // ---- Phase F: inverse row FFT, take real part, add bias, store ----
  fft16<-1>(re, im);

  const float* brow = bias + (size_t)p * 256 + (size_t)r * 16;
  float* orow = out + rowoff;
#pragma unroll
  for (int c4 = 0; c4 < 4; ++c4) {
    const float4 bv = ((const float4*)brow)[c4];
    float4 o;
    o.x = re[c4 * 4 + 0] + bv.x;
    o.y = re[c4 * 4 + 1] + bv.y;
    o.z = re[c4 * 4 + 2] + bv.z;
    o.w = re[c4 * 4 + 3] + bv.w;
    ((float4*)orow)[c4] = o;
  }
}

extern "C" void kernel_launch(void* const* d_in, const int* in_sizes, int n_in,
                              void* d_out, int out_size, void* d_ws,
                              size_t ws_size, hipStream_t stream) {
  (void)in_sizes;
  (void)n_in;
  (void)out_size;
  (void)d_ws;
  (void)ws_size;
  const float* x = (const float*)d_in[0];
  const float* logits = (const float*)d_in[1];
  const float* mu = (const float*)d_in[2];
  const float* sigma = (const float*)d_in[3];
  const float* bias = (const float*)d_in[4];
  float* out = (float*)d_out;

  // 1024 patches x 4 batch-chunks of 16
  psm_kernel<<<dim3(PP * 4), dim3(256), 0, stream>>>(x, logits, mu, sigma,
                                                     bias, out);
}

// Round 5
// 146.676 us; speedup vs baseline: 1.0277x; 1.0277x over previous
//
#include <hip/hip_runtime.h>
#include <math.h>

#define HH 512
#define WW 512
#define PHH 16
#define PWW 16
#define QQ 3
#define NHH 32
#define NWW 32
#define PP 1024
#define BB 64

// Compiler-only memory fence. volatile inline asm with a "memory" clobber is
// a serialization point for memory ops in both the IR optimizers and
// ScheduleDAGInstrs (side-effecting instrs get chain edges to all mem refs)
// -> no LDS op crosses. Deliberately NOT sched_barrier(0): pinning ALL code
// motion spiked peak register pressure and caused spills (rounds 3/4).
__device__ __forceinline__ void wfence() {
  asm volatile("" ::: "memory");
}

// Butterfly with COMPILE-TIME twiddle index T (0..7), radix-2 DIT, n=16.
// SGN=+1: forward exp(-i 2pi jk/16); SGN=-1: unscaled inverse.
// Trivial twiddles (T=0: w=1; T=4: w=-+i; T=2/6: w=(+-c,+-c)) are specialized
// so the compiler emits adds/subs instead of full complex multiplies.
template <int SGN, int T>
__device__ __forceinline__ void bfly(float& ar, float& ai, float& br, float& bi) {
  float tr, ti;
  if constexpr (T == 0) {
    tr = br;
    ti = bi;
  } else if constexpr (T == 4) {
    if constexpr (SGN > 0) { tr = bi;  ti = -br; }
    else                   { tr = -bi; ti = br;  }
  } else if constexpr (T == 2) {
    constexpr float c = 0.70710678118654752440f;
    if constexpr (SGN > 0) { tr = c * (br + bi); ti = c * (bi - br); }
    else                   { tr = c * (br - bi); ti = c * (bi + br); }
  } else if constexpr (T == 6) {
    constexpr float c = 0.70710678118654752440f;
    if constexpr (SGN > 0) { tr = c * (bi - br);  ti = -c * (br + bi); }
    else                   { tr = -c * (br + bi); ti = c * (br - bi);  }
  } else {
    // T in {1,3,5,7}: full complex multiply with literal constants.
    constexpr float c1 = 0.92387953251128675613f;   // cos(pi/8)
    constexpr float s1 = 0.38268343236508977173f;   // sin(pi/8)
    constexpr float wr = (T == 1) ? c1 : (T == 3) ? s1 : (T == 5) ? -s1 : -c1;
    constexpr float wi0 = (T == 1) ? -s1 : (T == 3) ? -c1 : (T == 5) ? -c1 : -s1;
    constexpr float wi = (SGN > 0) ? wi0 : -wi0;
    tr = br * wr - bi * wi;
    ti = br * wi + bi * wr;
  }
  br = ar - tr;
  bi = ai - ti;
  ar = ar + tr;
  ai = ai + ti;
}

// Fully-unrolled in-register 16-point complex FFT with literal twiddles.
template <int SGN>
__device__ __forceinline__ void fft16(float re[16], float im[16]) {
#define SW_(a, b)                              \
  { float t = re[a]; re[a] = re[b]; re[b] = t; \
    t = im[a]; im[a] = im[b]; im[b] = t; }
  SW_(1, 8) SW_(2, 4) SW_(3, 12) SW_(5, 10) SW_(7, 14) SW_(11, 13)
#undef SW_
#define BF_(a, b, T) bfly<SGN, T>(re[a], im[a], re[b], im[b]);
  // len=2
  BF_(0, 1, 0) BF_(2, 3, 0) BF_(4, 5, 0) BF_(6, 7, 0)
  BF_(8, 9, 0) BF_(10, 11, 0) BF_(12, 13, 0) BF_(14, 15, 0)
  // len=4
  BF_(0, 2, 0) BF_(1, 3, 4) BF_(4, 6, 0) BF_(5, 7, 4)
  BF_(8, 10, 0) BF_(9, 11, 4) BF_(12, 14, 0) BF_(13, 15, 4)
  // len=8
  BF_(0, 4, 0) BF_(1, 5, 2) BF_(2, 6, 4) BF_(3, 7, 6)
  BF_(8, 12, 0) BF_(9, 13, 2) BF_(10, 14, 4) BF_(11, 15, 6)
  // len=16
  BF_(0, 8, 0) BF_(1, 9, 1) BF_(2, 10, 2) BF_(3, 11, 3)
  BF_(4, 12, 4) BF_(5, 13, 5) BF_(6, 14, 6) BF_(7, 15, 7)
#undef BF_
}

// Block: 256 threads = 16 groups x 16 threads. Block handles one patch p and
// 16 batch indices; group g -> batch b0+g, thread r -> row r of 16x16 patch.
// Each group is a quarter-wave, so the LDS transposes are wave-internal:
// no __syncthreads needed after Phase A. Scalar stride-17 transpose buffer:
// proven 0 bank conflicts (rounds 0/3); float2/stride-18 gave 2.56M (round 4).
//
// amdgpu_waves_per_eu(1,4): the allocator's VGPR budget tracks its occupancy
// TARGET (empirical: budget ~= 256/target_waves_per_eu; LDS<=20KB implies
// target 8 -> budget 32 -> spills, rounds 2-4). Clamping the target to 4
// raises the budget to 64; the ~52-reg live set fits (round-0 evidence), and
// since ACTUAL allocation <=64 the hardware still grants 8 waves/EU.
__global__ __launch_bounds__(256)
__attribute__((amdgpu_waves_per_eu(1, 4)))
void psm_kernel(
    const float* __restrict__ x, const float* __restrict__ logits,
    const float* __restrict__ mu, const float* __restrict__ sigma,
    const float* __restrict__ bias, float* __restrict__ out) {
  __shared__ float S_lds[256];
  __shared__ float tbuf[16 * 272];  // 16 groups, 16 rows, stride 17

  const int tid = threadIdx.x;
  const int p = blockIdx.x >> 2;
  const int b0 = (blockIdx.x & 3) << 4;
  const int g = tid >> 4;
  const int r = tid & 15;
  const int b = b0 + g;
  const int nh = p >> 5;
  const int nw = p & 31;

  // ---- Phase B0: issue the x-row loads FIRST; latency hides under Phase A.
  const size_t rowoff =
      (size_t)b * (HH * WW) + (size_t)(nh * PHH + r) * WW + (size_t)(nw * PWW);
  const float* xrow = x + rowoff;
  float re[16], im[16];
#pragma unroll
  for (int c4 = 0; c4 < 4; ++c4) {
    const float4 v = ((const float4*)xrow)[c4];
    re[c4 * 4 + 0] = v.x;
    re[c4 * 4 + 1] = v.y;
    re[c4 * 4 + 2] = v.z;
    re[c4 * 4 + 3] = v.w;
  }

  // ---- Phase A: spectral filter S for this patch into LDS ----
  {
    const int fy_i = tid >> 4;
    const int fx_i = tid & 15;
    const float fy = (float)(fy_i < 8 ? fy_i : fy_i - 16) * (1.0f / 16.0f);
    const float fx = (float)(fx_i < 8 ? fx_i : fx_i - 16) * (1.0f / 16.0f);
    const float l0 = logits[p * QQ + 0];
    const float l1 = logits[p * QQ + 1];
    const float l2 = logits[p * QQ + 2];
    const float lm = fmaxf(l0, fmaxf(l1, l2));
    const float e0 = __expf(l0 - lm);
    const float e1 = __expf(l1 - lm);
    const float e2 = __expf(l2 - lm);
    const float inv = 1.0f / (e0 + e1 + e2);
    const float wq[3] = {e0 * inv, e1 * inv, e2 * inv};
    float s = 0.0f;
#pragma unroll
    for (int q = 0; q < QQ; ++q) {
      const float muy = mu[(p * QQ + q) * 2 + 0];
      const float mux = mu[(p * QQ + q) * 2 + 1];
      const float isy = 1.0f / sigma[(p * QQ + q) * 2 + 0];
      const float isx = 1.0f / sigma[(p * QQ + q) * 2 + 1];
      const float dy1 = (fy - muy) * isy;
      const float dx1 = (fx - mux) * isx;
      const float dy2 = (fy + muy) * isy;
      const float dx2 = (fx + mux) * isx;
      const float g1 = __expf(-0.5f * (dy1 * dy1 + dx1 * dx1));
      const float g2 = __expf(-0.5f * (dy2 * dy2 + dx2 * dx2));
      s += wq[q] * (g1 + g2);
    }
    // fold jitter and the ifft2 1/256 normalization into S
    S_lds[tid] = (s + 1e-6f) * (1.0f / 256.0f);
  }
  __syncthreads();  // the ONLY block barrier: S_lds is read by all waves

  // ---- Phase B: forward row FFT ----
#pragma unroll
  for (int c = 0; c < 16; ++c) im[c] = 0.0f;  // literal zeros fold thru stage 1-2

  fft16<1>(re, im);

  // ---- Phase C: transpose via wave-local LDS, single reused buffer ----
  float* m = &tbuf[g * 272];
#pragma unroll
  for (int c = 0; c < 16; ++c) m[r * 17 + c] = re[c];
  wfence();
#pragma unroll
  for (int k = 0; k < 16; ++k) re[k] = m[k * 17 + r];
  wfence();
#pragma unroll
  for (int c = 0; c < 16; ++c) m[r * 17 + c] = im[c];
  wfence();
#pragma unroll
  for (int k = 0; k < 16; ++k) im[k] = m[k * 17 + r];
  wfence();

  // ---- Phase D: column FFT, multiply by S, inverse column FFT ----
  fft16<1>(re, im);
#pragma unroll
  for (int k = 0; k < 16; ++k) {
    const float s = S_lds[k * 16 + r];
    re[k] *= s;
    im[k] *= s;
  }
  fft16<-1>(re, im);

  // ---- Phase E: transpose back (column write, row read), reused buffer ----
#pragma unroll
  for (int k = 0; k < 16; ++k) m[k * 17 + r] = re[k];
  wfence();
#pragma unroll
  for (int c = 0; c < 16; ++c) re[c] = m[r * 17 + c];
  wfence();
#pragma unroll
  for (int k = 0; k < 16; ++k) m[k * 17 + r] = im[k];
  wfence();
#pragma unroll
  for (int c = 0; c < 16; ++c) im[c] = m[r * 17 + c];

  // ---- Phase F: inverse row FFT, take real part, add bias, store ----
  fft16<-1>(re, im);

  const float* brow = bias + (size_t)p * 256 + (size_t)r * 16;
  float* orow = out + rowoff;
#pragma unroll
  for (int c4 = 0; c4 < 4; ++c4) {
    const float4 bv = ((const float4*)brow)[c4];
    float4 o;
    o.x = re[c4 * 4 + 0] + bv.x;
    o.y = re[c4 * 4 + 1] + bv.y;
    o.z = re[c4 * 4 + 2] + bv.z;
    o.w = re[c4 * 4 + 3] + bv.w;
    ((float4*)orow)[c4] = o;
  }
}

extern "C" void kernel_launch(void* const* d_in, const int* in_sizes, int n_in,
                              void* d_out, int out_size, void* d_ws,
                              size_t ws_size, hipStream_t stream) {
  (void)in_sizes;
  (void)n_in;
  (void)out_size;
  (void)d_ws;
  (void)ws_size;
  const float* x = (const float*)d_in[0];
  const float* logits = (const float*)d_in[1];
  const float* mu = (const float*)d_in[2];
  const float* sigma = (const float*)d_in[3];
  const float* bias = (const float*)d_in[4];
  float* out = (float*)d_out;

  // 1024 patches x 4 batch-chunks of 16
  psm_kernel<<<dim3(PP * 4), dim3(256), 0, stream>>>(x, logits, mu, sigma,
                                                     bias, out);
}